// Round 8
// baseline (2034.201 us; speedup 1.0000x reference)
//
#include <hip/hip_runtime.h>
#include <hip/hip_bf16.h>

// PointerNetwork: B=4096, L=10, IN=8, H=512, W=512. fp32 in/out, ws=256MiB.
// log_softmax over size-1 axes => hi==he==0. Surviving compute:
//   enc GRU, ew3 = h_enc @ w3^T, dec GRU, a4 = h_dec @ w4^T,
//   out_seq = tanh(ew3+a4)@v2, out_ori = h_dec @ wori[:,H:2H]^T + bori.
// Round 8: persistent recurrence kernel (512 blocks, 2/CU via
// __launch_bounds__(256,2)) with SOFTWARE per-row-group barriers
// (64 monotonic device-scope counters; block (bx,by) only depends on the
// 8 blocks sharing by). Cooperative API dropped (round-7 launch failure).

#define B_   4096
#define L_   10
#define IN_  8
#define H_   512
#define H3_  1536
#define W_   512
#define ORI_BASE (B_ * L_ * L_)   // 409600

typedef __attribute__((ext_vector_type(8))) short s8v;
typedef __attribute__((ext_vector_type(4))) float f4v;

#define LOG2E  1.4426950408889634f
#define LOG2E2 2.8853900817779268f

__device__ __forceinline__ float sig_fast(float x) {
  float e = __builtin_amdgcn_exp2f(-x * LOG2E);
  return __builtin_amdgcn_rcpf(1.f + e);
}
__device__ __forceinline__ float tanh_fast(float x) {
  float e = __builtin_amdgcn_exp2f(x * LOG2E2);
  return 1.f - 2.f * __builtin_amdgcn_rcpf(e + 1.f);
}
__device__ __forceinline__ short f2bf(float f) {
  __hip_bfloat16 h = __float2bfloat16(f);
  return __builtin_bit_cast(short, h);
}
__device__ __forceinline__ float bf2f(short s) {
  __hip_bfloat16 h = __builtin_bit_cast(__hip_bfloat16, s);
  return __bfloat162float(h);
}
__device__ __forceinline__ void stc(float* p, float v) { *p = v; }
__device__ __forceinline__ void stc(short* p, float v) { *p = f2bf(v); }

// ---- fused fp32->bf16 conversion of all 6 tensors in one launch ----
__global__ __launch_bounds__(256) void convert_all(
    const float* __restrict__ s0, const float* __restrict__ s1,
    const float* __restrict__ s2, const float* __restrict__ s3,
    const float* __restrict__ s4, const float* __restrict__ s5,
    short* __restrict__ d0, short* __restrict__ d1, short* __restrict__ d2,
    short* __restrict__ d3, short* __restrict__ d4, short* __restrict__ d5)
{
  long i = (long)blockIdx.x * 256 + threadIdx.x;
  const float* s; short* d; long o;
  if      (i < 786432)  { s = s0; d = d0; o = i; }
  else if (i < 1572864) { s = s1; d = d1; o = i - 786432; }
  else if (i < 2359296) { s = s2; d = d2; o = i - 1572864; }
  else if (i < 2621440) { s = s3; d = d3; o = i - 2359296; }
  else if (i < 2883584) { s = s4; d = d4; o = i - 2621440; }
  else                  { s = s5; d = d5; o = i - 2883584; }
  d[o] = f2bf(s[o]);
}

// ---- fold embedding into encoder input weight; one wave per g-row ----
__global__ __launch_bounds__(256) void build_wc(
    const float* __restrict__ enc_wih, const float* __restrict__ emb_w,
    const float* __restrict__ emb_b, const float* __restrict__ enc_bih,
    float* __restrict__ Wc, float* __restrict__ bc)
{
  __shared__ float se[H_ * IN_];
  __shared__ float sb[H_];
  const int tid = threadIdx.x;
  for (int i = tid; i < H_ * IN_; i += 256) se[i] = emb_w[i];
  for (int i = tid; i < H_; i += 256) sb[i] = emb_b[i];
  __syncthreads();
  int g = (blockIdx.x * 256 + tid) >> 6;
  int lane = tid & 63;
  const float* wr = enc_wih + (long)g * H_ + lane * 8;
  float w8[8];
#pragma unroll
  for (int j = 0; j < 8; ++j) w8[j] = wr[j];
  float acc[9] = {};
#pragma unroll
  for (int kk = 0; kk < 8; ++kk) {
    int k = lane * 8 + kk;
#pragma unroll
    for (int j = 0; j < 8; ++j) acc[j] += w8[kk] * se[k * IN_ + j];
    acc[8] += w8[kk] * sb[k];
  }
#pragma unroll
  for (int j = 0; j < 9; ++j)
#pragma unroll
    for (int off = 32; off; off >>= 1) acc[j] += __shfl_down(acc[j], off, 64);
  if (lane == 0) {
#pragma unroll
    for (int j = 0; j < 8; ++j) Wc[g * IN_ + j] = acc[j];
    bc[g] = acc[8] + enc_bih[g];
  }
}

// ---- software barrier among the 8 blocks sharing a row-group ----
// bar: 64 counters, 64-int stride (256B). Monotonic: expected = 8 * n_calls.
__device__ __forceinline__ void group_barrier(int* bar, int by, int expected) {
  __threadfence();            // release our hist stores device-wide
  __syncthreads();
  if (threadIdx.x == 0) {
    int* c = bar + by * 64;
    __hip_atomic_fetch_add(c, 1, __ATOMIC_ACQ_REL, __HIP_MEMORY_SCOPE_AGENT);
    while (__hip_atomic_load(c, __ATOMIC_ACQUIRE, __HIP_MEMORY_SCOPE_AGENT) < expected)
      __builtin_amdgcn_s_sleep(1);
  }
  __syncthreads();
}

// ---- 64x64x3-gate tile GEMM (K=512) ----
__device__ __forceinline__ void tile_gemm3(
    const short* __restrict__ Aslice,   // (B,H) bf16
    const short* __restrict__ Wg,       // (3H,H) bf16
    long row0, int col0, int tid, int wave, int lane,
    short* As, short* Bs, f4v acc[3][4])
{
  const int r16 = lane & 15, quad = lane >> 4;
  for (int k0 = 0; k0 < H_; k0 += 32) {
    {
      int m = tid >> 2, k8 = (tid & 3) * 8;
      __builtin_amdgcn_global_load_lds(
          (const __attribute__((address_space(1))) void*)(Aslice + (row0 + m) * H_ + k0 + k8),
          (__attribute__((address_space(3))) void*)(As + tid * 8), 16, 0, 0);
    }
#pragma unroll
    for (int r = 0; r < 3; ++r) {
      int idx = r * 256 + tid;
      int m = idx >> 2, k8 = (idx & 3) * 8;
      int g = m >> 6, cc = m & 63;
      __builtin_amdgcn_global_load_lds(
          (const __attribute__((address_space(1))) void*)(Wg + ((long)g * H_ + col0 + cc) * H_ + k0 + k8),
          (__attribute__((address_space(3))) void*)(Bs + idx * 8), 16, 0, 0);
    }
    __syncthreads();
    s8v af[4], bf[3];
#pragma unroll
    for (int i = 0; i < 4; ++i)
      af[i] = *(const s8v*)&As[(i * 16 + r16) * 32 + quad * 8];
#pragma unroll
    for (int g = 0; g < 3; ++g)
      bf[g] = *(const s8v*)&Bs[(g * 64 + wave * 16 + r16) * 32 + quad * 8];
#pragma unroll
    for (int g = 0; g < 3; ++g)
#pragma unroll
      for (int i = 0; i < 4; ++i)
        acc[g][i] = __builtin_amdgcn_mfma_f32_16x16x32_bf16(af[i], bf[g], acc[g][i], 0, 0, 0);
    __syncthreads();
  }
}

// ---- the whole recurrence: 10 enc + 10 dec steps, one persistent launch ----
__global__ __launch_bounds__(256, 2) void recurrence(
    const float* __restrict__ items,    // (B,L,IN) fp32
    const short* __restrict__ decb,     // (B,H) bf16
    const short* __restrict__ whh_e, const float* __restrict__ bhh_e,
    const short* __restrict__ whh_d, const float* __restrict__ bhh_d,
    const short* __restrict__ wih_d, const float* __restrict__ bih_d,
    const float* __restrict__ Wc, const float* __restrict__ bc,
    short* __restrict__ enc_hist,       // (11,B,H) bf16; slice 0 unused
    short* __restrict__ dec_hist,       // (10,B,H) bf16
    int* __restrict__ bar)              // 64 group counters, zeroed
{
  __shared__ short As[64 * 32];    // 4 KB (reused as items stage in enc epilogue)
  __shared__ short Bs[192 * 32];   // 12 KB
  const int tid = threadIdx.x;
  const int bx = blockIdx.x & 7, by = blockIdx.x >> 3;
  const int col0 = bx * 64;
  const long row0 = (long)by * 64;
  const int wave = tid >> 6, lane = tid & 63;
  const int r16 = lane & 15, quad = lane >> 4;
  const int col = col0 + wave * 16 + r16;
  const long BH = (long)B_ * H_;
  int sync_no = 0;

  // ---- decoder xg into registers (computed once; no cross-block dep) ----
  f4v xgr[3][4] = {};
  tile_gemm3(decb, wih_d, row0, col0, tid, wave, lane, As, Bs, xgr);
  {
    float b0 = bih_d[col], b1 = bih_d[col + H_], b2 = bih_d[col + 2 * H_];
#pragma unroll
    for (int i = 0; i < 4; ++i)
#pragma unroll
      for (int rg = 0; rg < 4; ++rg) {
        xgr[0][i][rg] += b0; xgr[1][i][rg] += b1; xgr[2][i][rg] += b2;
      }
  }

  // encoder per-column constants
  float wc[3][8], bcv[3];
#pragma unroll
  for (int g = 0; g < 3; ++g) {
    const float* wr = Wc + ((long)g * H_ + col) * IN_;
#pragma unroll
    for (int j = 0; j < 8; ++j) wc[g][j] = wr[j];
    bcv[g] = bc[g * H_ + col];
  }
  float behr = bhh_e[col], behz = bhh_e[col + H_], behn = bhh_e[col + 2 * H_];
  float bdhr = bhh_d[col], bdhz = bhh_d[col + H_], bdhn = bhh_d[col + 2 * H_];

  float hm[4][4];                      // fp32 master h, registers only
#pragma unroll
  for (int i = 0; i < 4; ++i)
#pragma unroll
    for (int rg = 0; rg < 4; ++rg) hm[i][rg] = 0.f;

  // ---- Encoder: 10 steps ----
  for (int t = 0; t < L_; ++t) {
    f4v acc[3][4] = {};
    if (t > 0)
      tile_gemm3(enc_hist + (long)t * BH, whh_e, row0, col0, tid, wave, lane, As, Bs, acc);
    // stage this step's items rows into LDS (reuse As)
    float* itemS = (float*)As;
    {
      int i2 = tid * 2;
      int m = i2 >> 3, j = i2 & 7;
      const float* it = items + (row0 + m) * (L_ * IN_) + t * IN_;
      itemS[i2] = it[j];
      itemS[i2 + 1] = it[j + 1];
    }
    __syncthreads();
    short* hout = enc_hist + (long)(t + 1) * BH;
#pragma unroll
    for (int i = 0; i < 4; ++i) {
#pragma unroll
      for (int rg = 0; rg < 4; ++rg) {
        int rl = i * 16 + quad * 4 + rg;
        const float* it = itemS + rl * 8;
        float xr = bcv[0], xz = bcv[1], xn = bcv[2];
#pragma unroll
        for (int j = 0; j < 8; ++j) {
          float iv = it[j];
          xr += iv * wc[0][j]; xz += iv * wc[1][j]; xn += iv * wc[2][j];
        }
        float r = sig_fast(xr + acc[0][i][rg] + behr);
        float z = sig_fast(xz + acc[1][i][rg] + behz);
        float n = tanh_fast(xn + r * (acc[2][i][rg] + behn));
        float hv = (1.f - z) * n + z * hm[i][rg];
        hm[i][rg] = hv;
        hout[(row0 + rl) * H_ + col] = f2bf(hv);
      }
    }
    ++sync_no;
    group_barrier(bar, by, 8 * sync_no);
  }

  // ---- Decoder: 10 steps ----
  for (int t = 0; t < L_; ++t) {
    const short* prev = (t == 0) ? enc_hist + (long)10 * BH
                                 : dec_hist + (long)(t - 1) * BH;
    f4v acc[3][4] = {};
    tile_gemm3(prev, whh_d, row0, col0, tid, wave, lane, As, Bs, acc);
    short* hout = dec_hist + (long)t * BH;
#pragma unroll
    for (int i = 0; i < 4; ++i) {
#pragma unroll
      for (int rg = 0; rg < 4; ++rg) {
        int rl = i * 16 + quad * 4 + rg;
        float r = sig_fast(xgr[0][i][rg] + acc[0][i][rg] + bdhr);
        float z = sig_fast(xgr[1][i][rg] + acc[1][i][rg] + bdhz);
        float n = tanh_fast(xgr[2][i][rg] + r * (acc[2][i][rg] + bdhn));
        float hv = (1.f - z) * n + z * hm[i][rg];
        hm[i][rg] = hv;
        hout[(row0 + rl) * H_ + col] = f2bf(hv);
      }
    }
    if (t < L_ - 1) {
      ++sync_no;
      group_barrier(bar, by, 8 * sync_no);
    }
  }
}

// ---- bf16 MFMA GEMM (epilogue ew3/a4): C[M,N] = A @ B^T, bf16 out ----
__global__ __launch_bounds__(256) void gemm_bf16(
    const short* __restrict__ A, long lda,
    const short* __restrict__ Bw, long ldb,
    short* __restrict__ C, long ldc, int K)
{
  __shared__ short As[128 * 32];
  __shared__ short Bs[128 * 32];
  const int tid = threadIdx.x;
  const long row0 = (long)blockIdx.y * 128;
  const long col0 = (long)blockIdx.x * 128;
  const int wave = tid >> 6, lane = tid & 63;
  const int wm = (wave & 1) * 64, wn = (wave >> 1) * 64;
  const int r16 = lane & 15, quad = lane >> 4;
  f4v acc[4][4] = {};

  for (int k0 = 0; k0 < K; k0 += 32) {
#pragma unroll
    for (int r = 0; r < 2; ++r) {
      int idx = r * 256 + tid;
      int m = idx >> 2;
      int k8 = (idx & 3) * 8;
      __builtin_amdgcn_global_load_lds(
          (const __attribute__((address_space(1))) void*)(A + (row0 + m) * lda + k0 + k8),
          (__attribute__((address_space(3))) void*)(As + idx * 8), 16, 0, 0);
      __builtin_amdgcn_global_load_lds(
          (const __attribute__((address_space(1))) void*)(Bw + (col0 + m) * ldb + k0 + k8),
          (__attribute__((address_space(3))) void*)(Bs + idx * 8), 16, 0, 0);
    }
    __syncthreads();
    s8v af[4], bf[4];
#pragma unroll
    for (int i = 0; i < 4; ++i)
      af[i] = *(const s8v*)&As[(wm + i * 16 + r16) * 32 + quad * 8];
#pragma unroll
    for (int j = 0; j < 4; ++j)
      bf[j] = *(const s8v*)&Bs[(wn + j * 16 + r16) * 32 + quad * 8];
#pragma unroll
    for (int i = 0; i < 4; ++i)
#pragma unroll
      for (int j = 0; j < 4; ++j)
        acc[i][j] = __builtin_amdgcn_mfma_f32_16x16x32_bf16(af[i], bf[j], acc[i][j], 0, 0, 0);
    __syncthreads();
  }

#pragma unroll
  for (int i = 0; i < 4; ++i) {
    long rbase = row0 + wm + i * 16 + quad * 4;
#pragma unroll
    for (int j = 0; j < 4; ++j) {
      long c = col0 + wn + j * 16 + r16;
#pragma unroll
      for (int rg = 0; rg < 4; ++rg)
        stc(&C[(rbase + rg) * ldc + c], acc[i][j][rg]);
    }
  }
}

// ---- batched out_seq: one block per b; LDS-tile 10 enc-l + 10 dec-t rows ----
__global__ __launch_bounds__(256) void out_seq_all(
    const short* __restrict__ ew3,   // (Lenc, B, W) bf16
    const short* __restrict__ a4,    // (Ldec, B, W) bf16
    const float* __restrict__ v2,
    float* __restrict__ out)
{
  __shared__ short se[L_ * W_];
  __shared__ short sa[L_ * W_];
  const int b = blockIdx.x;
  const int tid = threadIdx.x;
  const int wave = tid >> 6, lane = tid & 63;
  for (int i = tid; i < L_ * W_ / 8; i += 256) {
    int l = i >> 6, c = i & 63;
    *(s8v*)(se + i * 8) = *(const s8v*)(ew3 + ((long)l * B_ + b) * W_ + c * 8);
    *(s8v*)(sa + i * 8) = *(const s8v*)(a4 + ((long)l * B_ + b) * W_ + c * 8);
  }
  float v2r[8];
#pragma unroll
  for (int j = 0; j < 8; ++j) v2r[j] = v2[lane * 8 + j];
  __syncthreads();

#pragma unroll
  for (int pp = 0; pp < 25; ++pp) {
    int p = wave * 25 + pp;       // 100 (t,l) pairs over 4 waves
    int t = p / L_, l = p - t * L_;
    s8v ev = *(const s8v*)(se + l * W_ + lane * 8);
    s8v av = *(const s8v*)(sa + t * W_ + lane * 8);
    float acc = 0.f;
#pragma unroll
    for (int j = 0; j < 8; ++j)
      acc += tanh_fast(bf2f(ev[j]) + bf2f(av[j])) * v2r[j];
#pragma unroll
    for (int off = 32; off; off >>= 1) acc += __shfl_down(acc, off, 64);
    if (lane == 0) out[((long)b * L_ + t) * L_ + l] = acc;
  }
}

// ---- batched out_ori: one wave per (b,t) ----
__global__ __launch_bounds__(256) void out_ori_all(
    const short* __restrict__ dh,    // (Ldec, B, H) bf16
    const float* __restrict__ wori, const float* __restrict__ bori,
    float* __restrict__ out)
{
  int wid = (blockIdx.x * 256 + threadIdx.x) >> 6;   // b*L + t
  int lane = threadIdx.x & 63;
  int b = wid / L_, t = wid - b * L_;
  s8v hv = *(const s8v*)(dh + ((long)t * B_ + b) * H_ + lane * 8);
  float hf[8];
#pragma unroll
  for (int j = 0; j < 8; ++j) hf[j] = bf2f(hv[j]);
  float res[6];
#pragma unroll
  for (int o = 0; o < 6; ++o) {
    const float* wr = wori + (long)o * H3_ + H_ + lane * 8;
    float acc = 0.f;
#pragma unroll
    for (int j = 0; j < 8; ++j) acc += hf[j] * wr[j];
#pragma unroll
    for (int off = 32; off; off >>= 1) acc += __shfl_down(acc, off, 64);
    res[o] = acc;
  }
  if (lane == 0) {
    float* po = out + ORI_BASE + ((long)b * L_ + t) * 6;
#pragma unroll
    for (int o = 0; o < 6; ++o) po[o] = res[o] + bori[o];
  }
}

extern "C" void kernel_launch(void* const* d_in, const int* in_sizes, int n_in,
                              void* d_out, int out_size, void* d_ws, size_t ws_size,
                              hipStream_t stream)
{
  const float* items   = (const float*)d_in[0];
  const float* dec_in  = (const float*)d_in[1];
  const float* emb_w   = (const float*)d_in[2];
  const float* emb_b   = (const float*)d_in[3];
  const float* enc_wih = (const float*)d_in[4];
  const float* enc_whh = (const float*)d_in[5];
  const float* enc_bih = (const float*)d_in[6];
  const float* enc_bhh = (const float*)d_in[7];
  const float* dec_wih = (const float*)d_in[8];
  const float* dec_whh = (const float*)d_in[9];
  const float* dec_bih = (const float*)d_in[10];
  const float* dec_bhh = (const float*)d_in[11];
  const float* w3      = (const float*)d_in[14];
  const float* w4      = (const float*)d_in[15];
  const float* v2      = (const float*)d_in[20];
  const float* wori    = (const float*)d_in[23];
  const float* bori    = (const float*)d_in[24];
  float* out = (float*)d_out;

  char* ws = (char*)d_ws;
  size_t off = 0;
  auto alloc = [&](size_t bytes) { size_t o = off; off += (bytes + 255) & ~255UL; return o; };
  int*   bar      = (int*)  (ws + alloc(64 * 64 * 4));                   // 16 KiB
  float* Wc       = (float*)(ws + alloc(H3_ * IN_ * 4));
  float* bc       = (float*)(ws + alloc(H3_ * 4));
  short* enc_hist = (short*)(ws + alloc((size_t)11 * B_ * H_ * 2));      // 44 MiB
  short* dec_hist = (short*)(ws + alloc((size_t)L_ * B_ * H_ * 2));      // 40 MiB
  short* ew3      = (short*)(ws + alloc((size_t)L_ * B_ * W_ * 2));      // 40 MiB
  short* a4       = (short*)(ws + alloc((size_t)L_ * B_ * W_ * 2));      // 40 MiB
  short* whh_e    = (short*)(ws + alloc((size_t)H3_ * H_ * 2));
  short* whh_d    = (short*)(ws + alloc((size_t)H3_ * H_ * 2));
  short* wih_d    = (short*)(ws + alloc((size_t)H3_ * H_ * 2));
  short* w3b      = (short*)(ws + alloc((size_t)W_ * H_ * 2));
  short* w4b      = (short*)(ws + alloc((size_t)W_ * H_ * 2));
  short* decb     = (short*)(ws + alloc((size_t)B_ * H_ * 2));

  // ---- prep ----
  hipMemsetAsync(bar, 0, 64 * 64 * 4, stream);
  convert_all<<<19456, 256, 0, stream>>>(
      enc_whh, dec_whh, dec_wih, w3, w4, dec_in,
      whh_e, whh_d, wih_d, w3b, w4b, decb);
  build_wc<<<384, 256, 0, stream>>>(enc_wih, emb_w, emb_b, enc_bih, Wc, bc);

  // ---- recurrence: one persistent launch with software group barriers ----
  recurrence<<<512, 256, 0, stream>>>(
      items, decb, whh_e, enc_bhh, whh_d, dec_bhh, wih_d, dec_bih,
      Wc, bc, enc_hist, dec_hist, bar);

  // ---- batched epilogue ----
  gemm_bf16<<<dim3(4, 320), 256, 0, stream>>>(
      enc_hist + (size_t)B_ * H_, H_, w3b, H_, ew3, W_, H_);
  gemm_bf16<<<dim3(4, 320), 256, 0, stream>>>(
      dec_hist, H_, w4b, H_, a4, W_, H_);
  out_seq_all<<<B_, 256, 0, stream>>>(ew3, a4, v2, out);
  out_ori_all<<<(B_ * L_) / 4, 256, 0, stream>>>(dec_hist, wori, bori, out);
}

// Round 10
// 786.500 us; speedup vs baseline: 2.5864x; 2.5864x over previous
//
#include <hip/hip_runtime.h>
#include <hip/hip_bf16.h>

// PointerNetwork: B=4096, L=10, IN=8, H=512, W=512. fp32 in/out, ws=256MiB.
// log_softmax over size-1 axes => hi==he==0. Surviving compute:
//   enc GRU, ew3 = h_enc @ w3^T, dec GRU, a4 = h_dec @ w4^T,
//   out_seq = tanh(ew3+a4)@v2, out_ori = h_dec @ wori[:,H:2H]^T + bori.
// Round 10: round-9 persistent recurrence with the A-chunk staging bug fixed:
// a 64x128-short chunk is 2048 ulls (8/thread), not 1024 — round 9 left half
// of each LDS row uninitialized => NaN via MFMA. Memory model unchanged:
// relaxed agent-scope write-through stores + s_waitcnt drain + relaxed
// counter; relaxed agent-scope 8B loads for prev-hist; weights cached in L2.

#define B_   4096
#define L_   10
#define IN_  8
#define H_   512
#define H3_  1536
#define W_   512
#define ORI_BASE (B_ * L_ * L_)   // 409600

typedef __attribute__((ext_vector_type(8))) short s8v;
typedef __attribute__((ext_vector_type(4))) float f4v;

#define LOG2E  1.4426950408889634f
#define LOG2E2 2.8853900817779268f

__device__ __forceinline__ float sig_fast(float x) {
  float e = __builtin_amdgcn_exp2f(-x * LOG2E);
  return __builtin_amdgcn_rcpf(1.f + e);
}
__device__ __forceinline__ float tanh_fast(float x) {
  float e = __builtin_amdgcn_exp2f(x * LOG2E2);
  return 1.f - 2.f * __builtin_amdgcn_rcpf(e + 1.f);
}
__device__ __forceinline__ short f2bf(float f) {
  __hip_bfloat16 h = __float2bfloat16(f);
  return __builtin_bit_cast(short, h);
}
__device__ __forceinline__ float bf2f(short s) {
  __hip_bfloat16 h = __builtin_bit_cast(__hip_bfloat16, s);
  return __bfloat162float(h);
}
__device__ __forceinline__ void stc(float* p, float v) { *p = v; }
__device__ __forceinline__ void stc(short* p, float v) { *p = f2bf(v); }

// ---- fused fp32->bf16 conversion of all 6 tensors in one launch ----
__global__ __launch_bounds__(256) void convert_all(
    const float* __restrict__ s0, const float* __restrict__ s1,
    const float* __restrict__ s2, const float* __restrict__ s3,
    const float* __restrict__ s4, const float* __restrict__ s5,
    short* __restrict__ d0, short* __restrict__ d1, short* __restrict__ d2,
    short* __restrict__ d3, short* __restrict__ d4, short* __restrict__ d5)
{
  long i = (long)blockIdx.x * 256 + threadIdx.x;
  const float* s; short* d; long o;
  if      (i < 786432)  { s = s0; d = d0; o = i; }
  else if (i < 1572864) { s = s1; d = d1; o = i - 786432; }
  else if (i < 2359296) { s = s2; d = d2; o = i - 1572864; }
  else if (i < 2621440) { s = s3; d = d3; o = i - 2359296; }
  else if (i < 2883584) { s = s4; d = d4; o = i - 2621440; }
  else                  { s = s5; d = d5; o = i - 2883584; }
  d[o] = f2bf(s[o]);
}

// ---- fold embedding into encoder input weight; one wave per g-row ----
__global__ __launch_bounds__(256) void build_wc(
    const float* __restrict__ enc_wih, const float* __restrict__ emb_w,
    const float* __restrict__ emb_b, const float* __restrict__ enc_bih,
    float* __restrict__ Wc, float* __restrict__ bc)
{
  __shared__ float se[H_ * IN_];
  __shared__ float sb[H_];
  const int tid = threadIdx.x;
  for (int i = tid; i < H_ * IN_; i += 256) se[i] = emb_w[i];
  for (int i = tid; i < H_; i += 256) sb[i] = emb_b[i];
  __syncthreads();
  int g = (blockIdx.x * 256 + tid) >> 6;
  int lane = tid & 63;
  const float* wr = enc_wih + (long)g * H_ + lane * 8;
  float w8[8];
#pragma unroll
  for (int j = 0; j < 8; ++j) w8[j] = wr[j];
  float acc[9] = {};
#pragma unroll
  for (int kk = 0; kk < 8; ++kk) {
    int k = lane * 8 + kk;
#pragma unroll
    for (int j = 0; j < 8; ++j) acc[j] += w8[kk] * se[k * IN_ + j];
    acc[8] += w8[kk] * sb[k];
  }
#pragma unroll
  for (int j = 0; j < 9; ++j)
#pragma unroll
    for (int off = 32; off; off >>= 1) acc[j] += __shfl_down(acc[j], off, 64);
  if (lane == 0) {
#pragma unroll
    for (int j = 0; j < 8; ++j) Wc[g * IN_ + j] = acc[j];
    bc[g] = acc[8] + enc_bih[g];
  }
}

// ---- fine-grained barrier among the 8 blocks sharing a row-group ----
__device__ __forceinline__ void group_barrier(int* bar, int by, int expected) {
  __builtin_amdgcn_s_waitcnt(0);     // drain our device-scope hist stores
  __syncthreads();
  if (threadIdx.x == 0) {
    int* c = bar + by * 64;
    __hip_atomic_fetch_add(c, 1, __ATOMIC_RELAXED, __HIP_MEMORY_SCOPE_AGENT);
    while (__hip_atomic_load(c, __ATOMIC_RELAXED, __HIP_MEMORY_SCOPE_AGENT) < expected)
      __builtin_amdgcn_s_sleep(2);
  }
  __syncthreads();
}

// ---- packed device-scope bf16-pair store (lanes r16 even/odd pair up) ----
__device__ __forceinline__ void store_pair_dev(short* base_even, float hv, int r16) {
  unsigned v = (unsigned short)f2bf(hv);
  unsigned o = (unsigned)__shfl_xor((int)v, 1, 64);
  if ((r16 & 1) == 0) {
    unsigned packed = v | (o << 16);
    __hip_atomic_store((unsigned*)base_even, packed,
                       __ATOMIC_RELAXED, __HIP_MEMORY_SCOPE_AGENT);
  }
}

// ---- 64x64x3-gate tile GEMM (K=512). A streamed in 4 padded 128-wide
// chunks via device-scope 8B loads (bypass L2); B (weights) streamed in
// 32-wide chunks via the normal cached global_load_lds path. ----
__device__ __forceinline__ void gemm3_step(
    const short* __restrict__ Aslice,   // (B,H) bf16
    const short* __restrict__ Wg,       // (3H,H) bf16
    long row0, int col0, int tid, int wave, int lane,
    short* AsC, short* Bs, f4v acc[3][4])
{
  const int r16 = lane & 15, quad = lane >> 4;
  for (int kc = 0; kc < H_; kc += 128) {
    // A chunk: 64 rows x 128 shorts = 2048 ull; 8 device-scope loads/thread
#pragma unroll
    for (int r = 0; r < 8; ++r) {
      int idx = r * 256 + tid;
      int m = idx >> 5;            // row 0..63
      int k4 = idx & 31;           // ull within chunk row (32 ull = 128 shorts)
      const unsigned long long* src =
          (const unsigned long long*)(Aslice + (row0 + m) * H_ + kc) + k4;
      unsigned long long v =
          __hip_atomic_load(src, __ATOMIC_RELAXED, __HIP_MEMORY_SCOPE_AGENT);
      *(unsigned long long*)(AsC + m * 136 + k4 * 4) = v;   // stride 136: 2-way banks
    }
#pragma unroll
    for (int k0s = 0; k0s < 4; ++k0s) {
      int k0 = kc + k0s * 32;
#pragma unroll
      for (int r = 0; r < 3; ++r) {             // B: 192x32, 3 DMA instrs
        int idx = r * 256 + tid;
        int m = idx >> 2, k8 = (idx & 3) * 8;
        int g = m >> 6, cc = m & 63;
        __builtin_amdgcn_global_load_lds(
            (const __attribute__((address_space(1))) void*)(Wg + ((long)g * H_ + col0 + cc) * H_ + k0 + k8),
            (__attribute__((address_space(3))) void*)(Bs + idx * 8), 16, 0, 0);
      }
      __syncthreads();
      s8v af[4], bf[3];
#pragma unroll
      for (int i = 0; i < 4; ++i)
        af[i] = *(const s8v*)&AsC[(i * 16 + r16) * 136 + k0s * 32 + quad * 8];
#pragma unroll
      for (int g = 0; g < 3; ++g)
        bf[g] = *(const s8v*)&Bs[(g * 64 + wave * 16 + r16) * 32 + quad * 8];
#pragma unroll
      for (int g = 0; g < 3; ++g)
#pragma unroll
        for (int i = 0; i < 4; ++i)
          acc[g][i] = __builtin_amdgcn_mfma_f32_16x16x32_bf16(af[i], bf[g], acc[g][i], 0, 0, 0);
      __syncthreads();
    }
  }
}

// ---- the whole recurrence: 10 enc + 10 dec steps, one persistent launch ----
__global__ __launch_bounds__(256, 2) void recurrence(
    const float* __restrict__ items,    // (B,L,IN) fp32
    const short* __restrict__ decb,     // (B,H) bf16
    const short* __restrict__ whh_e, const float* __restrict__ bhh_e,
    const short* __restrict__ whh_d, const float* __restrict__ bhh_d,
    const short* __restrict__ wih_d, const float* __restrict__ bih_d,
    const float* __restrict__ Wc, const float* __restrict__ bc,
    short* __restrict__ enc_hist,       // (11,B,H) bf16; slice 0 unused
    short* __restrict__ dec_hist,       // (10,B,H) bf16
    int* __restrict__ bar)              // 64 group counters, zeroed
{
  __shared__ short AsC[64 * 136];  // 17 KB padded A chunk (also items stage)
  __shared__ short Bs[192 * 32];   // 12 KB
  const int tid = threadIdx.x;
  const int bx = blockIdx.x & 7, by = blockIdx.x >> 3;
  const int col0 = bx * 64;
  const long row0 = (long)by * 64;
  const int wave = tid >> 6, lane = tid & 63;
  const int r16 = lane & 15, quad = lane >> 4;
  const int col = col0 + wave * 16 + r16;
  const long BH = (long)B_ * H_;
  int sync_no = 0;

  // ---- decoder xg into registers (computed once; decb from prior dispatch) ----
  f4v xgr[3][4] = {};
  gemm3_step(decb, wih_d, row0, col0, tid, wave, lane, AsC, Bs, xgr);
  {
    float b0 = bih_d[col], b1 = bih_d[col + H_], b2 = bih_d[col + 2 * H_];
#pragma unroll
    for (int i = 0; i < 4; ++i)
#pragma unroll
      for (int rg = 0; rg < 4; ++rg) {
        xgr[0][i][rg] += b0; xgr[1][i][rg] += b1; xgr[2][i][rg] += b2;
      }
  }

  // encoder per-column constants
  float wc[3][8], bcv[3];
#pragma unroll
  for (int g = 0; g < 3; ++g) {
    const float* wr = Wc + ((long)g * H_ + col) * IN_;
#pragma unroll
    for (int j = 0; j < 8; ++j) wc[g][j] = wr[j];
    bcv[g] = bc[g * H_ + col];
  }
  float behr = bhh_e[col], behz = bhh_e[col + H_], behn = bhh_e[col + 2 * H_];
  float bdhr = bhh_d[col], bdhz = bhh_d[col + H_], bdhn = bhh_d[col + 2 * H_];

  float hm[4][4];                      // fp32 master h, registers only
#pragma unroll
  for (int i = 0; i < 4; ++i)
#pragma unroll
    for (int rg = 0; rg < 4; ++rg) hm[i][rg] = 0.f;

  // ---- Encoder: 10 steps ----
  for (int t = 0; t < L_; ++t) {
    f4v acc[3][4] = {};
    if (t > 0)
      gemm3_step(enc_hist + (long)t * BH, whh_e, row0, col0, tid, wave, lane,
                 AsC, Bs, acc);
    // stage this step's items rows into LDS (reuse AsC)
    float* itemS = (float*)AsC;
    {
      int i2 = tid * 2;
      int m = i2 >> 3, j = i2 & 7;
      const float* it = items + (row0 + m) * (L_ * IN_) + t * IN_;
      itemS[i2] = it[j];
      itemS[i2 + 1] = it[j + 1];
    }
    __syncthreads();
    short* hout = enc_hist + (long)(t + 1) * BH;
#pragma unroll
    for (int i = 0; i < 4; ++i) {
#pragma unroll
      for (int rg = 0; rg < 4; ++rg) {
        int rl = i * 16 + quad * 4 + rg;
        const float* it = itemS + rl * 8;
        float xr = bcv[0], xz = bcv[1], xn = bcv[2];
#pragma unroll
        for (int j = 0; j < 8; ++j) {
          float iv = it[j];
          xr += iv * wc[0][j]; xz += iv * wc[1][j]; xn += iv * wc[2][j];
        }
        float r = sig_fast(xr + acc[0][i][rg] + behr);
        float z = sig_fast(xz + acc[1][i][rg] + behz);
        float n = tanh_fast(xn + r * (acc[2][i][rg] + behn));
        float hv = (1.f - z) * n + z * hm[i][rg];
        hm[i][rg] = hv;
        store_pair_dev(&hout[(row0 + rl) * H_ + (col & ~1)], hv, r16);
      }
    }
    ++sync_no;
    group_barrier(bar, by, 8 * sync_no);
  }

  // ---- Decoder: 10 steps ----
  for (int t = 0; t < L_; ++t) {
    const short* prev = (t == 0) ? enc_hist + (long)10 * BH
                                 : dec_hist + (long)(t - 1) * BH;
    f4v acc[3][4] = {};
    gemm3_step(prev, whh_d, row0, col0, tid, wave, lane, AsC, Bs, acc);
    short* hout = dec_hist + (long)t * BH;
#pragma unroll
    for (int i = 0; i < 4; ++i) {
#pragma unroll
      for (int rg = 0; rg < 4; ++rg) {
        int rl = i * 16 + quad * 4 + rg;
        float r = sig_fast(xgr[0][i][rg] + acc[0][i][rg] + bdhr);
        float z = sig_fast(xgr[1][i][rg] + acc[1][i][rg] + bdhz);
        float n = tanh_fast(xgr[2][i][rg] + r * (acc[2][i][rg] + bdhn));
        float hv = (1.f - z) * n + z * hm[i][rg];
        hm[i][rg] = hv;
        store_pair_dev(&hout[(row0 + rl) * H_ + (col & ~1)], hv, r16);
      }
    }
    if (t < L_ - 1) {
      ++sync_no;
      group_barrier(bar, by, 8 * sync_no);
    }
  }
}

// ---- bf16 MFMA GEMM (epilogue ew3/a4): C[M,N] = A @ B^T, bf16 out ----
__global__ __launch_bounds__(256) void gemm_bf16(
    const short* __restrict__ A, long lda,
    const short* __restrict__ Bw, long ldb,
    short* __restrict__ C, long ldc, int K)
{
  __shared__ short As[128 * 32];
  __shared__ short Bs[128 * 32];
  const int tid = threadIdx.x;
  const long row0 = (long)blockIdx.y * 128;
  const long col0 = (long)blockIdx.x * 128;
  const int wave = tid >> 6, lane = tid & 63;
  const int wm = (wave & 1) * 64, wn = (wave >> 1) * 64;
  const int r16 = lane & 15, quad = lane >> 4;
  f4v acc[4][4] = {};

  for (int k0 = 0; k0 < K; k0 += 32) {
#pragma unroll
    for (int r = 0; r < 2; ++r) {
      int idx = r * 256 + tid;
      int m = idx >> 2;
      int k8 = (idx & 3) * 8;
      __builtin_amdgcn_global_load_lds(
          (const __attribute__((address_space(1))) void*)(A + (row0 + m) * lda + k0 + k8),
          (__attribute__((address_space(3))) void*)(As + idx * 8), 16, 0, 0);
      __builtin_amdgcn_global_load_lds(
          (const __attribute__((address_space(1))) void*)(Bw + (col0 + m) * ldb + k0 + k8),
          (__attribute__((address_space(3))) void*)(Bs + idx * 8), 16, 0, 0);
    }
    __syncthreads();
    s8v af[4], bf[4];
#pragma unroll
    for (int i = 0; i < 4; ++i)
      af[i] = *(const s8v*)&As[(wm + i * 16 + r16) * 32 + quad * 8];
#pragma unroll
    for (int j = 0; j < 4; ++j)
      bf[j] = *(const s8v*)&Bs[(wn + j * 16 + r16) * 32 + quad * 8];
#pragma unroll
    for (int i = 0; i < 4; ++i)
#pragma unroll
      for (int j = 0; j < 4; ++j)
        acc[i][j] = __builtin_amdgcn_mfma_f32_16x16x32_bf16(af[i], bf[j], acc[i][j], 0, 0, 0);
    __syncthreads();
  }

#pragma unroll
  for (int i = 0; i < 4; ++i) {
    long rbase = row0 + wm + i * 16 + quad * 4;
#pragma unroll
    for (int j = 0; j < 4; ++j) {
      long c = col0 + wn + j * 16 + r16;
#pragma unroll
      for (int rg = 0; rg < 4; ++rg)
        stc(&C[(rbase + rg) * ldc + c], acc[i][j][rg]);
    }
  }
}

// ---- batched out_seq: one block per b; LDS-tile 10 enc-l + 10 dec-t rows ----
__global__ __launch_bounds__(256) void out_seq_all(
    const short* __restrict__ ew3,   // (Lenc, B, W) bf16
    const short* __restrict__ a4,    // (Ldec, B, W) bf16
    const float* __restrict__ v2,
    float* __restrict__ out)
{
  __shared__ short se[L_ * W_];
  __shared__ short sa[L_ * W_];
  const int b = blockIdx.x;
  const int tid = threadIdx.x;
  const int wave = tid >> 6, lane = tid & 63;
  for (int i = tid; i < L_ * W_ / 8; i += 256) {
    int l = i >> 6, c = i & 63;
    *(s8v*)(se + i * 8) = *(const s8v*)(ew3 + ((long)l * B_ + b) * W_ + c * 8);
    *(s8v*)(sa + i * 8) = *(const s8v*)(a4 + ((long)l * B_ + b) * W_ + c * 8);
  }
  float v2r[8];
#pragma unroll
  for (int j = 0; j < 8; ++j) v2r[j] = v2[lane * 8 + j];
  __syncthreads();

#pragma unroll
  for (int pp = 0; pp < 25; ++pp) {
    int p = wave * 25 + pp;       // 100 (t,l) pairs over 4 waves
    int t = p / L_, l = p - t * L_;
    s8v ev = *(const s8v*)(se + l * W_ + lane * 8);
    s8v av = *(const s8v*)(sa + t * W_ + lane * 8);
    float acc = 0.f;
#pragma unroll
    for (int j = 0; j < 8; ++j)
      acc += tanh_fast(bf2f(ev[j]) + bf2f(av[j])) * v2r[j];
#pragma unroll
    for (int off = 32; off; off >>= 1) acc += __shfl_down(acc, off, 64);
    if (lane == 0) out[((long)b * L_ + t) * L_ + l] = acc;
  }
}

// ---- batched out_ori: one wave per (b,t) ----
__global__ __launch_bounds__(256) void out_ori_all(
    const short* __restrict__ dh,    // (Ldec, B, H) bf16
    const float* __restrict__ wori, const float* __restrict__ bori,
    float* __restrict__ out)
{
  int wid = (blockIdx.x * 256 + threadIdx.x) >> 6;   // b*L + t
  int lane = threadIdx.x & 63;
  int b = wid / L_, t = wid - b * L_;
  s8v hv = *(const s8v*)(dh + ((long)t * B_ + b) * H_ + lane * 8);
  float hf[8];
#pragma unroll
  for (int j = 0; j < 8; ++j) hf[j] = bf2f(hv[j]);
  float res[6];
#pragma unroll
  for (int o = 0; o < 6; ++o) {
    const float* wr = wori + (long)o * H3_ + H_ + lane * 8;
    float acc = 0.f;
#pragma unroll
    for (int j = 0; j < 8; ++j) acc += hf[j] * wr[j];
#pragma unroll
    for (int off = 32; off; off >>= 1) acc += __shfl_down(acc, off, 64);
    res[o] = acc;
  }
  if (lane == 0) {
    float* po = out + ORI_BASE + ((long)b * L_ + t) * 6;
#pragma unroll
    for (int o = 0; o < 6; ++o) po[o] = res[o] + bori[o];
  }
}

extern "C" void kernel_launch(void* const* d_in, const int* in_sizes, int n_in,
                              void* d_out, int out_size, void* d_ws, size_t ws_size,
                              hipStream_t stream)
{
  const float* items   = (const float*)d_in[0];
  const float* dec_in  = (const float*)d_in[1];
  const float* emb_w   = (const float*)d_in[2];
  const float* emb_b   = (const float*)d_in[3];
  const float* enc_wih = (const float*)d_in[4];
  const float* enc_whh = (const float*)d_in[5];
  const float* enc_bih = (const float*)d_in[6];
  const float* enc_bhh = (const float*)d_in[7];
  const float* dec_wih = (const float*)d_in[8];
  const float* dec_whh = (const float*)d_in[9];
  const float* dec_bih = (const float*)d_in[10];
  const float* dec_bhh = (const float*)d_in[11];
  const float* w3      = (const float*)d_in[14];
  const float* w4      = (const float*)d_in[15];
  const float* v2      = (const float*)d_in[20];
  const float* wori    = (const float*)d_in[23];
  const float* bori    = (const float*)d_in[24];
  float* out = (float*)d_out;

  char* ws = (char*)d_ws;
  size_t off = 0;
  auto alloc = [&](size_t bytes) { size_t o = off; off += (bytes + 255) & ~255UL; return o; };
  int*   bar      = (int*)  (ws + alloc(64 * 64 * 4));                   // 16 KiB
  float* Wc       = (float*)(ws + alloc(H3_ * IN_ * 4));
  float* bc       = (float*)(ws + alloc(H3_ * 4));
  short* enc_hist = (short*)(ws + alloc((size_t)11 * B_ * H_ * 2));      // 44 MiB
  short* dec_hist = (short*)(ws + alloc((size_t)L_ * B_ * H_ * 2));      // 40 MiB
  short* ew3      = (short*)(ws + alloc((size_t)L_ * B_ * W_ * 2));      // 40 MiB
  short* a4       = (short*)(ws + alloc((size_t)L_ * B_ * W_ * 2));      // 40 MiB
  short* whh_e    = (short*)(ws + alloc((size_t)H3_ * H_ * 2));
  short* whh_d    = (short*)(ws + alloc((size_t)H3_ * H_ * 2));
  short* wih_d    = (short*)(ws + alloc((size_t)H3_ * H_ * 2));
  short* w3b      = (short*)(ws + alloc((size_t)W_ * H_ * 2));
  short* w4b      = (short*)(ws + alloc((size_t)W_ * H_ * 2));
  short* decb     = (short*)(ws + alloc((size_t)B_ * H_ * 2));

  // ---- prep ----
  hipMemsetAsync(bar, 0, 64 * 64 * 4, stream);
  convert_all<<<19456, 256, 0, stream>>>(
      enc_whh, dec_whh, dec_wih, w3, w4, dec_in,
      whh_e, whh_d, wih_d, w3b, w4b, decb);
  build_wc<<<384, 256, 0, stream>>>(enc_wih, emb_w, emb_b, enc_bih, Wc, bc);

  // ---- recurrence: one persistent launch with fine-grained group barriers ----
  recurrence<<<512, 256, 0, stream>>>(
      items, decb, whh_e, enc_bhh, whh_d, dec_bhh, wih_d, dec_bih,
      Wc, bc, enc_hist, dec_hist, bar);

  // ---- batched epilogue ----
  gemm_bf16<<<dim3(4, 320), 256, 0, stream>>>(
      enc_hist + (size_t)B_ * H_, H_, w3b, H_, ew3, W_, H_);
  gemm_bf16<<<dim3(4, 320), 256, 0, stream>>>(
      dec_hist, H_, w4b, H_, a4, W_, H_);
  out_seq_all<<<B_, 256, 0, stream>>>(ew3, a4, v2, out);
  out_ori_all<<<(B_ * L_) / 4, 256, 0, stream>>>(dec_hist, wori, bori, out);
}